// Round 3
// baseline (700.979 us; speedup 1.0000x reference)
//
#include <hip/hip_runtime.h>

#define NODES 2047
#define DD 256

typedef __attribute__((ext_vector_type(8))) __bf16 bf16x8;
typedef __attribute__((ext_vector_type(4))) float f32x4;

__device__ __forceinline__ float sigf(float x) { return 1.0f / (1.0f + __expf(-x)); }
__device__ __forceinline__ float tanhf_fast(float x) {
    float ax = fabsf(x);
    float t = __expf(-2.0f * ax);
    float r = (1.0f - t) / (1.0f + t);
    return x < 0.0f ? -r : r;
}
__device__ __forceinline__ ushort f2b(float x) {
    union { float f; uint u; } v; v.f = x;
    uint r = v.u + 0x7FFFu + ((v.u >> 16) & 1u);
    return (ushort)(r >> 16);
}
__device__ __forceinline__ float b2f(ushort b) {
    union { uint u; float f; } v; v.u = ((uint)b) << 16;
    return v.f;
}

#define GLD16(gp, lp) __builtin_amdgcn_global_load_lds( \
    (const __attribute__((address_space(1))) void*)(gp), \
    (__attribute__((address_space(3))) void*)(lp), 16, 0, 0)
#define WAITV(N) asm volatile("s_waitcnt vmcnt(" #N ")" ::: "memory")
#define CFENCE() asm volatile("" ::: "memory")

// ---------- prep: dense gathered A for level 0 (fp32 emb -> bf16 xb[65536][320]) ----
__global__ __launch_bounds__(256) void prep_x(const int* __restrict__ wids,
                                              const float* __restrict__ emb,
                                              ushort* __restrict__ xb) {
    long i = (long)blockIdx.x * 256 + threadIdx.x;    // ushort4 slots: 65536*80
    if (i >= 65536L * 80) return;
    int row = (int)(i / 80);
    int slot = (int)(i - (long)row * 80);
    int k = slot * 4;
    float4 v = {0.f, 0.f, 0.f, 0.f};
    if (k < 300) v = *(const float4*)(emb + (long)wids[row] * 300 + k);
    ushort4 o = {f2b(v.x), f2b(v.y), f2b(v.z), f2b(v.w)};
    ((ushort4*)xb)[i] = o;
}
__global__ __launch_bounds__(256) void prep_u(const float* __restrict__ Ul,
                                              const float* __restrict__ Ur,
                                              ushort* __restrict__ o) {
    int i = blockIdx.x * 256 + threadIdx.x;          // U_t[1280][512]
    if (i >= 1280 * 512) return;
    int c = i >> 9, k = i & 511;
    o[i] = f2b(k < 256 ? Ul[k * 1280 + c] : Ur[(k - 256) * 1280 + c]);
}
__global__ __launch_bounds__(256) void prep_wx(const float* __restrict__ Wx,
                                               ushort* __restrict__ o) {
    int i = blockIdx.x * 256 + threadIdx.x;          // WxT[1280][320]
    if (i >= 1280 * 320) return;
    int c = i / 320, k = i - c * 320;
    o[i] = f2b(k < 300 ? Wx[k * 1280 + c] : 0.0f);
}

// ---------- fused level GEMM (bf16 MFMA, counted-vmcnt dbuf) + LSTM cell ----------
// Block tile: 128 rows x (5 gates x 32 d). 4 waves as 2x2 (wave: 64 rows x 80 cols).
// Double-buffered LDS; next-tile global_load_lds stays in flight across barriers
// via per-wave s_waitcnt vmcnt(N) + raw s_barrier (T3-min + T4).
template<bool IS_L0>
__global__ __launch_bounds__(256, 4)
void level_mfma(const ushort* __restrict__ Asrc,   // xb (L0) or h_all bf16
                const ushort* __restrict__ Bt,     // [1280][KF] bf16 (col-major weights)
                const float*  __restrict__ bias,   // (1280,)
                const float*  __restrict__ c_in,   // (B, 2n, 256) fp32, tree only
                ushort*       __restrict__ h_all,  // (B, 2047, 256) bf16
                float*        __restrict__ c_out,  // (B, n, 256) fp32
                int M, int n_out, int off_out, int off_prev, int log2n)
{
    constexpr int KF = IS_L0 ? 320 : 512;
    constexpr int NT = KF / 32;
    __shared__ bf16x8 A_lds[2][8][64];    // 16 KB
    __shared__ bf16x8 B_lds[2][10][64];   // 20 KB

    const int tid = threadIdx.x;
    const int l   = tid & 63;
    const int w   = tid >> 6;
    const int wr  = w >> 1;
    const int wc  = w & 1;
    const int row0 = blockIdx.x * 128;
    const int d0   = blockIdx.y * 32;
    const int l15  = l & 15;
    const int kg   = l >> 4;

    // per-lane global source pointers for A (2 fm-blocks per wave)
    const ushort* aptr[2];
    #pragma unroll
    for (int t = 0; t < 2; t++) {
        int fmb = 2 * w + t;
        int rg = row0 + fmb * 16 + l15;
        if (rg >= M) rg = 0;                       // clamp (stores predicated)
        long rb;
        if (IS_L0) {
            rb = (long)rg * 320;
        } else {
            int b = rg >> log2n;
            int j = rg & (n_out - 1);
            rb = ((long)(b * NODES + off_prev)) * DD + (long)j * 512;
        }
        aptr[t] = Asrc + rb + kg * 8;
    }
    // per-lane global source pointers for B (cg = w, w+4, [w+8 for w<2])
    const ushort* bptr[3];
    #pragma unroll
    for (int t = 0; t < 3; t++) {
        int cg = w + 4 * t;
        if (cg >= 10) cg = w;                      // dummy, unused
        int cl = cg * 16 + l15;
        int g = cl >> 5, ds = cl & 31;
        int gcol = g * 256 + d0 + ds;
        bptr[t] = Bt + (long)gcol * KF + kg * 8;
    }

    f32x4 acc[4][5];
    f32x4 zero = {0.0f, 0.0f, 0.0f, 0.0f};
    #pragma unroll
    for (int a = 0; a < 4; a++)
        #pragma unroll
        for (int g = 0; g < 5; g++) acc[a][g] = zero;

    #define STAGE(T, BB) do {                                   \
        int _off = (T) * 32;                                    \
        GLD16(aptr[0] + _off, &A_lds[BB][2 * w + 0][0]);        \
        GLD16(aptr[1] + _off, &A_lds[BB][2 * w + 1][0]);        \
        GLD16(bptr[0] + _off, &B_lds[BB][w][0]);                \
        GLD16(bptr[1] + _off, &B_lds[BB][w + 4][0]);            \
        if (w < 2) GLD16(bptr[2] + _off, &B_lds[BB][w + 8][0]); \
    } while (0)

    STAGE(0, 0);
    #pragma unroll
    for (int t = 0; t < NT; ++t) {
        const int cur = t & 1;
        if (t + 1 < NT) {
            STAGE(t + 1, cur ^ 1);
            if (w < 2) { WAITV(5); } else { WAITV(4); }
        } else {
            WAITV(0);
        }
        __builtin_amdgcn_s_barrier();
        CFENCE();
        bf16x8 af[4], bfr[5];
        #pragma unroll
        for (int fm = 0; fm < 4; fm++) af[fm] = A_lds[cur][wr * 4 + fm][l];
        #pragma unroll
        for (int g = 0; g < 5; g++) bfr[g] = B_lds[cur][g * 2 + wc][l];
        #pragma unroll
        for (int fm = 0; fm < 4; fm++)
            #pragma unroll
            for (int g = 0; g < 5; g++)
                acc[fm][g] = __builtin_amdgcn_mfma_f32_16x16x32_bf16(
                    af[fm], bfr[g], acc[fm][g], 0, 0, 0);
        CFENCE();
        __builtin_amdgcn_s_barrier();
    }
    #undef STAGE

    // ---- fused LSTM cell epilogue ----
    const int d = d0 + wc * 16 + l15;
    float bi[5];
    #pragma unroll
    for (int g = 0; g < 5; g++) bi[g] = bias[g * 256 + d];

    #pragma unroll
    for (int fm = 0; fm < 4; fm++) {
        #pragma unroll
        for (int j = 0; j < 4; j++) {
            int rg = row0 + wr * 64 + fm * 16 + kg * 4 + j;   // D: m=(l>>4)*4+j
            if (rg < M) {
                int b = rg >> log2n;
                int jj = rg & (n_out - 1);
                float gi  = acc[fm][0][j] + bi[0];
                float gfl = acc[fm][1][j] + bi[1];
                float gfr = acc[fm][2][j] + bi[2];
                float go  = acc[fm][3][j] + bi[3];
                float gu  = acc[fm][4][j] + bi[4];
                float c = sigf(gi) * tanhf_fast(gu);
                if (!IS_L0) {
                    long cb = ((long)b * (2 * n_out) + 2 * jj) * DD + d;
                    c += sigf(gfl) * c_in[cb] + sigf(gfr) * c_in[cb + DD];
                }
                float h = sigf(go) * tanhf_fast(c);
                h_all[((long)b * NODES + (off_out + jj)) * DD + d] = f2b(h);
                c_out[((long)b * n_out + jj) * DD + d] = c;
            }
        }
    }
}

// ---------- prediction head: (131008, 256) bf16 @ (256,5) + b ----------
__global__ __launch_bounds__(256)
void pred_kernel(const ushort* __restrict__ h_all, const float* __restrict__ pW,
                 const float* __restrict__ pb, float* __restrict__ out)
{
    __shared__ float Ws[1280];
    int tid = threadIdx.x;
    for (int i = tid; i < 1280; i += 256) Ws[i] = pW[i];
    __syncthreads();
    int lane = tid & 63, wave = tid >> 6;
    long row = (long)blockIdx.x * 4 + wave;      // 131008 = 32752*4
    ushort4 hv = ((const ushort4*)(h_all + row * DD))[lane];
    float x[4] = {b2f(hv.x), b2f(hv.y), b2f(hv.z), b2f(hv.w)};
    float a[5];
    #pragma unroll
    for (int g = 0; g < 5; g++) {
        a[g] = x[0] * Ws[(lane * 4 + 0) * 5 + g]
             + x[1] * Ws[(lane * 4 + 1) * 5 + g]
             + x[2] * Ws[(lane * 4 + 2) * 5 + g]
             + x[3] * Ws[(lane * 4 + 3) * 5 + g];
    }
    #pragma unroll
    for (int off = 32; off > 0; off >>= 1) {
        #pragma unroll
        for (int g = 0; g < 5; g++) a[g] += __shfl_down(a[g], off);
    }
    if (lane == 0) {
        #pragma unroll
        for (int g = 0; g < 5; g++) out[row * 5 + g] = a[g] + pb[g];
    }
}

extern "C" void kernel_launch(void* const* d_in, const int* in_sizes, int n_in,
                              void* d_out, int out_size, void* d_ws, size_t ws_size,
                              hipStream_t stream)
{
    const int*   wids = (const int*)  d_in[0];
    const float* emb  = (const float*)d_in[1];
    const float* Wx   = (const float*)d_in[2];
    const float* Ul   = (const float*)d_in[3];
    const float* Ur   = (const float*)d_in[4];
    const float* bias = (const float*)d_in[5];
    const float* pW   = (const float*)d_in[6];
    const float* pb   = (const float*)d_in[7];
    float* out = (float*)d_out;

    char* ws = (char*)d_ws;
    ushort* xb   = (ushort*)ws;  ws += (size_t)65536 * 320 * 2;       // 41.9 MB
    ushort* Ut   = (ushort*)ws;  ws += (size_t)1280 * 512 * 2;        //  1.3 MB
    ushort* WxT  = (ushort*)ws;  ws += (size_t)1280 * 320 * 2;        //  0.8 MB
    ushort* h_all= (ushort*)ws;  ws += (size_t)64 * NODES * DD * 2;   // 67.0 MB
    float*  c0   = (float*)ws;   ws += (size_t)64 * 1024 * DD * 4;    // 67.1 MB
    float*  c1   = (float*)ws;                                        // 33.5 MB

    prep_x<<<(65536 * 80 + 255) / 256, 256, 0, stream>>>(wids, emb, xb);
    prep_u<<<(1280 * 512 + 255) / 256, 256, 0, stream>>>(Ul, Ur, Ut);
    prep_wx<<<(1280 * 320 + 255) / 256, 256, 0, stream>>>(Wx, WxT);

    // level 0: gates = xb @ WxT^T, c_l = c_r = 0
    level_mfma<true><<<dim3(512, 8), 256, 0, stream>>>(
        xb, WxT, bias, nullptr, h_all, c0, 65536, 1024, 0, 0, 10);

    // tree levels 1..10
    for (int lvl = 1; lvl <= 10; lvl++) {
        int n = 1024 >> lvl;
        int M = 64 * n;
        int off_out = 2048 - (2048 >> lvl);
        int off_prev = 2048 - (4096 >> lvl);
        float* cin  = (lvl & 1) ? c0 : c1;
        float* cout = (lvl & 1) ? c1 : c0;
        level_mfma<false><<<dim3((M + 127) / 128, 8), 256, 0, stream>>>(
            h_all, Ut, bias, cin, h_all, cout,
            M, n, off_out, off_prev, 10 - lvl);
    }

    pred_kernel<<<32752, 256, 0, stream>>>(h_all, pW, pb, out);
}

// Round 4
// 685.948 us; speedup vs baseline: 1.0219x; 1.0219x over previous
//
#include <hip/hip_runtime.h>

#define NODES 2047
#define DD 256

typedef __attribute__((ext_vector_type(8))) __bf16 bf16x8;
typedef __attribute__((ext_vector_type(4))) float f32x4;

__device__ __forceinline__ float sigf(float x) { return 1.0f / (1.0f + __expf(-x)); }
__device__ __forceinline__ float tanhf_fast(float x) {
    float ax = fabsf(x);
    float t = __expf(-2.0f * ax);
    float r = (1.0f - t) / (1.0f + t);
    return x < 0.0f ? -r : r;
}
__device__ __forceinline__ ushort f2b(float x) {
    union { float f; uint u; } v; v.f = x;
    uint r = v.u + 0x7FFFu + ((v.u >> 16) & 1u);
    return (ushort)(r >> 16);
}
__device__ __forceinline__ float b2f(ushort b) {
    union { uint u; float f; } v; v.u = ((uint)b) << 16;
    return v.f;
}

#define GLD16(gp, lp) __builtin_amdgcn_global_load_lds( \
    (const __attribute__((address_space(1))) void*)(gp), \
    (__attribute__((address_space(3))) void*)(lp), 16, 0, 0)
#define WAITV(N) asm volatile("s_waitcnt vmcnt(" #N ")" ::: "memory")
#define CFENCE() asm volatile("" ::: "memory")

// ---------- prep: dense gathered A for level 0 (fp32 emb -> bf16 xb[65536][320]) ----
__global__ __launch_bounds__(256) void prep_x(const int* __restrict__ wids,
                                              const float* __restrict__ emb,
                                              ushort* __restrict__ xb) {
    long i = (long)blockIdx.x * 256 + threadIdx.x;    // ushort4 slots: 65536*80
    if (i >= 65536L * 80) return;
    int row = (int)(i / 80);
    int slot = (int)(i - (long)row * 80);
    int k = slot * 4;
    float4 v = {0.f, 0.f, 0.f, 0.f};
    if (k < 300) v = *(const float4*)(emb + (long)wids[row] * 300 + k);
    ushort4 o = {f2b(v.x), f2b(v.y), f2b(v.z), f2b(v.w)};
    ((ushort4*)xb)[i] = o;
}
__global__ __launch_bounds__(256) void prep_u(const float* __restrict__ Ul,
                                              const float* __restrict__ Ur,
                                              ushort* __restrict__ o) {
    int i = blockIdx.x * 256 + threadIdx.x;          // U_t[1280][512]
    if (i >= 1280 * 512) return;
    int c = i >> 9, k = i & 511;
    o[i] = f2b(k < 256 ? Ul[k * 1280 + c] : Ur[(k - 256) * 1280 + c]);
}
__global__ __launch_bounds__(256) void prep_wx(const float* __restrict__ Wx,
                                               ushort* __restrict__ o) {
    int i = blockIdx.x * 256 + threadIdx.x;          // WxT[1280][320]
    if (i >= 1280 * 320) return;
    int c = i / 320, k = i - c * 320;
    o[i] = f2b(k < 300 ? Wx[k * 1280 + c] : 0.0f);
}

// ---------- fused level GEMM (bf16 MFMA, counted-vmcnt dbuf) + LSTM cell ----------
// Block: 512 threads = 8 waves as 2(row)x4(col). Tile 128 rows x 320 cols
// (320 = 5 gates x 64 d). grid-y = 4 column slices (A re-read x4, was x8).
// Per wave per K-step: 1 A-load + 2-3 B-loads vs 20 MFMAs.
// Counted-vmcnt double-buffer: next-tile global_load_lds stays in flight
// across the raw s_barrier pair.
template<bool IS_L0>
__global__ __launch_bounds__(512)
void level_mfma(const ushort* __restrict__ Asrc,   // xb (L0) or h_all bf16
                const ushort* __restrict__ Bt,     // [1280][KF] bf16 (col-major weights)
                const float*  __restrict__ bias,   // (1280,)
                const float*  __restrict__ c_in,   // (B, 2n, 256) fp32, tree only
                ushort*       __restrict__ h_all,  // (B, 2047, 256) bf16
                float*        __restrict__ c_out,  // (B, n, 256) fp32
                int M, int n_out, int off_out, int off_prev, int log2n)
{
    constexpr int KF = IS_L0 ? 320 : 512;
    constexpr int NT = KF / 32;
    __shared__ bf16x8 A_lds[2][8][64];    // 16 KB
    __shared__ bf16x8 B_lds[2][20][64];   // 40 KB

    const int tid = threadIdx.x;
    const int l   = tid & 63;
    const int w   = tid >> 6;          // 8 waves
    const int wr  = w >> 2;            // row-wave 0..1
    const int wc  = w & 3;             // col-wave 0..3
    const int row0 = blockIdx.x * 128;
    const int d0   = blockIdx.y * 64;
    const int l15  = l & 15;
    const int kg   = l >> 4;

    // A: wave w stages fm-block w (16 rows)
    const ushort* aptr;
    {
        int rg = row0 + w * 16 + l15;
        if (rg >= M) rg = 0;                       // clamp (stores predicated)
        long rb;
        if (IS_L0) {
            rb = (long)rg * 320;
        } else {
            int b = rg >> log2n;
            int j = rg & (n_out - 1);
            rb = ((long)(b * NODES + off_prev)) * DD + (long)j * 512;
        }
        aptr = Asrc + rb + kg * 8;
    }
    // B: 20 cg-blocks (16 cols each); wave w stages cg = w, w+8, [w+16 if w<4]
    const ushort* bptr[3];
    #pragma unroll
    for (int t = 0; t < 3; t++) {
        int cg = w + 8 * t;
        if (cg >= 20) cg = w;                      // dummy, unused
        int g = cg >> 2;                           // gate
        int ds = (cg & 3) * 16 + l15;              // d within 64-slice
        int gcol = g * 256 + d0 + ds;
        bptr[t] = Bt + (long)gcol * KF + kg * 8;
    }

    f32x4 acc[4][5];
    f32x4 zero = {0.0f, 0.0f, 0.0f, 0.0f};
    #pragma unroll
    for (int a = 0; a < 4; a++)
        #pragma unroll
        for (int g = 0; g < 5; g++) acc[a][g] = zero;

    #define STAGE(T, BB) do {                                    \
        int _off = (T) * 32;                                     \
        GLD16(aptr + _off, &A_lds[BB][w][0]);                    \
        GLD16(bptr[0] + _off, &B_lds[BB][w][0]);                 \
        GLD16(bptr[1] + _off, &B_lds[BB][w + 8][0]);             \
        if (w < 4) GLD16(bptr[2] + _off, &B_lds[BB][w + 16][0]); \
    } while (0)

    STAGE(0, 0);
    #pragma unroll
    for (int t = 0; t < NT; ++t) {
        const int cur = t & 1;
        if (t + 1 < NT) {
            STAGE(t + 1, cur ^ 1);
            if (w < 4) { WAITV(4); } else { WAITV(3); }
        } else {
            WAITV(0);
        }
        __builtin_amdgcn_s_barrier();
        CFENCE();
        bf16x8 af[4], bfr[5];
        #pragma unroll
        for (int fm = 0; fm < 4; fm++) af[fm] = A_lds[cur][wr * 4 + fm][l];
        #pragma unroll
        for (int g = 0; g < 5; g++) bfr[g] = B_lds[cur][g * 4 + wc][l];
        #pragma unroll
        for (int fm = 0; fm < 4; fm++)
            #pragma unroll
            for (int g = 0; g < 5; g++)
                acc[fm][g] = __builtin_amdgcn_mfma_f32_16x16x32_bf16(
                    af[fm], bfr[g], acc[fm][g], 0, 0, 0);
        CFENCE();
        __builtin_amdgcn_s_barrier();
    }
    #undef STAGE

    // ---- fused LSTM cell epilogue ----
    const int d = d0 + wc * 16 + l15;
    float bi[5];
    #pragma unroll
    for (int g = 0; g < 5; g++) bi[g] = bias[g * 256 + d];

    #pragma unroll
    for (int fm = 0; fm < 4; fm++) {
        #pragma unroll
        for (int j = 0; j < 4; j++) {
            int rg = row0 + wr * 64 + fm * 16 + kg * 4 + j;   // D: m=(l>>4)*4+j
            if (rg < M) {
                int b = rg >> log2n;
                int jj = rg & (n_out - 1);
                float gi  = acc[fm][0][j] + bi[0];
                float gfl = acc[fm][1][j] + bi[1];
                float gfr = acc[fm][2][j] + bi[2];
                float go  = acc[fm][3][j] + bi[3];
                float gu  = acc[fm][4][j] + bi[4];
                float c = sigf(gi) * tanhf_fast(gu);
                if (!IS_L0) {
                    long cb = ((long)b * (2 * n_out) + 2 * jj) * DD + d;
                    c += sigf(gfl) * c_in[cb] + sigf(gfr) * c_in[cb + DD];
                }
                float h = sigf(go) * tanhf_fast(c);
                h_all[((long)b * NODES + (off_out + jj)) * DD + d] = f2b(h);
                c_out[((long)b * n_out + jj) * DD + d] = c;
            }
        }
    }
}

// ---------- prediction head: (131008, 256) bf16 @ (256,5) + b ----------
__global__ __launch_bounds__(256)
void pred_kernel(const ushort* __restrict__ h_all, const float* __restrict__ pW,
                 const float* __restrict__ pb, float* __restrict__ out)
{
    __shared__ float Ws[1280];
    int tid = threadIdx.x;
    for (int i = tid; i < 1280; i += 256) Ws[i] = pW[i];
    __syncthreads();
    int lane = tid & 63, wave = tid >> 6;
    long row = (long)blockIdx.x * 4 + wave;      // 131008 = 32752*4
    ushort4 hv = ((const ushort4*)(h_all + row * DD))[lane];
    float x[4] = {b2f(hv.x), b2f(hv.y), b2f(hv.z), b2f(hv.w)};
    float a[5];
    #pragma unroll
    for (int g = 0; g < 5; g++) {
        a[g] = x[0] * Ws[(lane * 4 + 0) * 5 + g]
             + x[1] * Ws[(lane * 4 + 1) * 5 + g]
             + x[2] * Ws[(lane * 4 + 2) * 5 + g]
             + x[3] * Ws[(lane * 4 + 3) * 5 + g];
    }
    #pragma unroll
    for (int off = 32; off > 0; off >>= 1) {
        #pragma unroll
        for (int g = 0; g < 5; g++) a[g] += __shfl_down(a[g], off);
    }
    if (lane == 0) {
        #pragma unroll
        for (int g = 0; g < 5; g++) out[row * 5 + g] = a[g] + pb[g];
    }
}

extern "C" void kernel_launch(void* const* d_in, const int* in_sizes, int n_in,
                              void* d_out, int out_size, void* d_ws, size_t ws_size,
                              hipStream_t stream)
{
    const int*   wids = (const int*)  d_in[0];
    const float* emb  = (const float*)d_in[1];
    const float* Wx   = (const float*)d_in[2];
    const float* Ul   = (const float*)d_in[3];
    const float* Ur   = (const float*)d_in[4];
    const float* bias = (const float*)d_in[5];
    const float* pW   = (const float*)d_in[6];
    const float* pb   = (const float*)d_in[7];
    float* out = (float*)d_out;

    char* ws = (char*)d_ws;
    ushort* xb   = (ushort*)ws;  ws += (size_t)65536 * 320 * 2;       // 41.9 MB
    ushort* Ut   = (ushort*)ws;  ws += (size_t)1280 * 512 * 2;        //  1.3 MB
    ushort* WxT  = (ushort*)ws;  ws += (size_t)1280 * 320 * 2;        //  0.8 MB
    ushort* h_all= (ushort*)ws;  ws += (size_t)64 * NODES * DD * 2;   // 67.0 MB
    float*  c0   = (float*)ws;   ws += (size_t)64 * 1024 * DD * 4;    // 67.1 MB
    float*  c1   = (float*)ws;                                        // 33.5 MB

    prep_x<<<(65536 * 80 + 255) / 256, 256, 0, stream>>>(wids, emb, xb);
    prep_u<<<(1280 * 512 + 255) / 256, 256, 0, stream>>>(Ul, Ur, Ut);
    prep_wx<<<(1280 * 320 + 255) / 256, 256, 0, stream>>>(Wx, WxT);

    // level 0: gates = xb @ WxT^T, c_l = c_r = 0
    level_mfma<true><<<dim3(512, 4), 512, 0, stream>>>(
        xb, WxT, bias, nullptr, h_all, c0, 65536, 1024, 0, 0, 10);

    // tree levels 1..10
    for (int lvl = 1; lvl <= 10; lvl++) {
        int n = 1024 >> lvl;
        int M = 64 * n;
        int off_out = 2048 - (2048 >> lvl);
        int off_prev = 2048 - (4096 >> lvl);
        float* cin  = (lvl & 1) ? c0 : c1;
        float* cout = (lvl & 1) ? c1 : c0;
        level_mfma<false><<<dim3((M + 127) / 128, 4), 512, 0, stream>>>(
            h_all, Ut, bias, cin, h_all, cout,
            M, n, off_out, off_prev, 10 - lvl);
    }

    pred_kernel<<<32752, 256, 0, stream>>>(h_all, pW, pb, out);
}